// Round 11
// baseline (251.372 us; speedup 1.0000x reference)
//
#include <hip/hip_runtime.h>
#include <hip/hip_cooperative_groups.h>
#include <math.h>

namespace cg = cooperative_groups;

namespace {

constexpr int F = 10;
constexpr int H = 64;
constexpr int P = 6;

// ---- additive-path 1D LUT (pair-packed float2 slots) ----
constexpr int   NLUT       = 1024;
constexpr float LUT_LO     = -14.5f;
constexpr float LUT_HI     = 6.5f;
constexpr float LUT_DX     = (LUT_HI - LUT_LO) / NLUT;
constexpr float LUT_INVDX  = NLUT / (LUT_HI - LUT_LO);
constexpr float LUT_POSMAX = (float)(NLUT - 2) + 0.999f;

// ---- pairwise-path 2D LUT: NB x NB grid, quad-packed float4 slots ----
constexpr int NB  = 128;
constexpr int N2D = P * NB * NB;
constexpr float A_LO  = -6.5f;
constexpr float A_SPAN = 13.0f;
constexpr int PI[P] = {0, 0, 0, 0, 1, 2};
constexpr int PJ[P] = {4, 7, 9, 3, 4, 3};
constexpr float B_LO[P]   = {-14.5f, -6.5f, -6.5f, -6.5f, -14.5f, -6.5f};
constexpr float B_SPAN[P] = { 19.0f,  13.0f, 13.0f, 13.0f,  19.0f, 13.0f};
constexpr float POSMAX2   = (float)(NB - 1) - 0.001f;

constexpr int WS_LUT1_OFF = 4 * N2D;
constexpr int WS_FLOATS   = 4 * N2D + 2 * F * NLUT;
constexpr int N_ENTRIES   = N2D + F * NLUT;      // 108544 build items

// Exact-grade GELU: x * Phi(x), Phi via A&S 7.1.26 erfc (|err| <= 1.5e-7).
__device__ __forceinline__ float gelu_exact(float x) {
    const float kInvSqrt2 = 0.70710678118654752440f;
    float u = x * kInvSqrt2;
    float a = fabsf(u);
    float t = __builtin_amdgcn_rcpf(fmaf(0.3275911f, a, 1.0f));
    float poly = t * fmaf(t, fmaf(t, fmaf(t, fmaf(t, 0.5307027145f,
                                                  -0.7265760135f),
                                           0.7107068705f),
                                   -0.142248368f),
                          0.127414796f);
    float e = __expf(-a * a);
    float half_erfc = poly * e;           // 0.5*erfc(|u|)
    float m = x * half_erfc;
    return (x >= 0.0f) ? (x - m) : m;
}

__device__ __forceinline__ void build_entry(
    int idx,
    const float* __restrict__ fw1, const float* __restrict__ fb1,
    const float* __restrict__ fw2, const float* __restrict__ fb2,
    const float* __restrict__ pw1, const float* __restrict__ pb1,
    const float* __restrict__ pw2, const float* __restrict__ pb2,
    float* __restrict__ ws)
{
    if (idx < N2D) {
        const int p   = idx / (NB * NB);
        const int rem = idx - p * (NB * NB);
        const int ia  = rem >> 7;
        const int jb  = rem & (NB - 1);
        const bool f4 = (p == 0) | (p == 4);
        const float blo   = f4 ? -14.5f : -6.5f;
        const float bstep = (f4 ? 19.0f : 13.0f) / (float)(NB - 1);
        const float astep = A_SPAN / (float)(NB - 1);
        const float sa = fmaf((float)ia, astep, A_LO);
        const float sb = fmaf((float)jb, bstep, blo);
        const float* wa = pw1 + (p * 2 + 0) * H;
        const float* wb = pw1 + (p * 2 + 1) * H;
        const float* bb = pb1 + p * H;
        const float* w2 = pw2 + p * H;
        float acc = pb2[p];
        #pragma unroll 8
        for (int h = 0; h < H; ++h) {
            acc = fmaf(gelu_exact(fmaf(sa, wa[h], fmaf(sb, wb[h], bb[h]))),
                       w2[h], acc);
        }
        // scatter into the <=4 quads referencing grid point (ia, jb)
        const int pbase = p * NB * NB;
        float* q = ws + 4 * (pbase + ia * NB + jb);
        q[0] = acc;
        if (jb > 0)           q[-4 + 1] = acc;
        if (ia > 0)           q[-4 * NB + 2] = acc;
        if (ia > 0 && jb > 0) q[-4 * (NB + 1) + 3] = acc;
    } else if (idx < N_ENTRIES) {
        const int k = idx - N2D;
        const int f = k >> 10;
        const int i = k & 1023;
        const float s = LUT_LO + (float)i * LUT_DX;
        const float* w1 = fw1 + f * H;
        const float* b1 = fb1 + f * H;
        const float* w2 = fw2 + f * H;
        float acc = fb2[f];
        #pragma unroll 8
        for (int h = 0; h < H; ++h) {
            acc = fmaf(gelu_exact(fmaf(s, w1[h], b1[h])), w2[h], acc);
        }
        ws[WS_LUT1_OFF + 2 * k] = acc;
        if (i > 0) ws[WS_LUT1_OFF + 2 * k - 1] = acc;
    }
}

__device__ __forceinline__ float bilerp4(const float4* __restrict__ lutp,
                                         float sa, float sb,
                                         float ainv, float blo, float binv) {
    float pa = fminf(fmaxf((sa - A_LO) * ainv, 0.0f), POSMAX2);
    float pb = fminf(fmaxf((sb - blo) * binv, 0.0f), POSMAX2);
    int ia = (int)pa;
    int jb = (int)pb;
    float fa = pa - (float)ia;
    float fb = pb - (float)jb;
    float4 q = lutp[ia * NB + jb];
    float v0 = fmaf(fb, q.y - q.x, q.x);
    float v1 = fmaf(fb, q.w - q.z, q.z);
    return fmaf(fa, v1 - v0, v0);
}

// ============== fused cooperative kernel: build LUTs, grid.sync, eval =====
// grid = 2048 blocks x 256 = 524288 threads = 8 blocks/CU (residency
// guaranteed by __launch_bounds__(256, 8) -> VGPR cap 64, LDS 0).
__global__ __launch_bounds__(256, 8) void fused_risk_kernel(
    const float* __restrict__ x,
    const float* __restrict__ raw_mean,
    const float* __restrict__ raw_std,
    const float* __restrict__ fw1,
    const float* __restrict__ fb1,
    const float* __restrict__ fw2,
    const float* __restrict__ fb2,
    const float* __restrict__ pw1,
    const float* __restrict__ pb1,
    const float* __restrict__ pw2,
    const float* __restrict__ pb2,
    float* __restrict__ ws,
    float* __restrict__ out,
    int nrows)
{
    const int gid = blockIdx.x * blockDim.x + threadIdx.x;

    // ---- phase 1: build LUTs (108544 of 524288 threads active)
    if (gid < N_ENTRIES) {
        build_entry(gid, fw1, fb1, fw2, fb2, pw1, pb1, pw2, pb2, ws);
    }

    // device-scope fence + grid barrier (per-XCD L2s are not coherent)
    cg::this_grid().sync();

    // ---- phase 2: per-row evaluation
    if (gid >= nrows) return;
    const float4* lut2 = reinterpret_cast<const float4*>(ws);
    const float2* lut1 = reinterpret_cast<const float2*>(ws + WS_LUT1_OFF);

    float v[F];
    {
        const float2* xp = reinterpret_cast<const float2*>(x + (size_t)gid * F);
        float2 a = xp[0], b = xp[1], c = xp[2], d = xp[3], e = xp[4];
        v[0] = a.x; v[1] = a.y; v[2] = b.x; v[3] = b.y;
        v[4] = c.x; v[5] = c.y; v[6] = d.x; v[7] = d.y;
        v[8] = e.x; v[9] = e.y;
    }

    float s[F];
    #pragma unroll
    for (int f = 0; f < F; ++f) {
        float ra = v[f];
        if (f == 4) ra = __logf(fmaxf(ra * 10.0f, 1e-6f));
        s[f] = (ra - raw_mean[f]) / raw_std[f];
    }

    float acc = 0.0f;

    #pragma unroll
    for (int f = 0; f < F; ++f) {
        float pos = fminf(fmaxf(fmaf(s[f], LUT_INVDX, -LUT_LO * LUT_INVDX), 0.0f), LUT_POSMAX);
        int i = (int)pos;
        float fr = pos - (float)i;
        float2 c = lut1[f * NLUT + i];
        acc += fmaf(fr, c.y - c.x, c.x);
    }

    constexpr float AINV = (float)(NB - 1) / A_SPAN;
    #pragma unroll
    for (int p = 0; p < P; ++p) {
        const float4* lutp = lut2 + p * NB * NB;
        const float binv = (float)(NB - 1) / B_SPAN[p];
        acc += bilerp4(lutp, s[PI[p]], s[PJ[p]], AINV, B_LO[p], binv);
    }

    out[gid] = acc;
}

// ============== fallback path A: two-kernel LUT (proven, ~104 us) =========
__global__ __launch_bounds__(256) void build_luts(
    const float* __restrict__ fw1, const float* __restrict__ fb1,
    const float* __restrict__ fw2, const float* __restrict__ fb2,
    const float* __restrict__ pw1, const float* __restrict__ pb1,
    const float* __restrict__ pw2, const float* __restrict__ pb2,
    float* __restrict__ ws)
{
    const int idx = blockIdx.x * blockDim.x + threadIdx.x;
    build_entry(idx, fw1, fb1, fw2, fb2, pw1, pb1, pw2, pb2, ws);
}

__global__ __launch_bounds__(256) void risk_lut2_kernel(
    const float* __restrict__ x,
    const float* __restrict__ raw_mean,
    const float* __restrict__ raw_std,
    const float* __restrict__ ws,
    float* __restrict__ out,
    int nrows)
{
    const float4* lut2 = reinterpret_cast<const float4*>(ws);
    const float2* lut1 = reinterpret_cast<const float2*>(ws + WS_LUT1_OFF);
    const int r = blockIdx.x * blockDim.x + threadIdx.x;
    if (r >= nrows) return;

    float v[F];
    {
        const float2* xp = reinterpret_cast<const float2*>(x + (size_t)r * F);
        float2 a = xp[0], b = xp[1], c = xp[2], d = xp[3], e = xp[4];
        v[0] = a.x; v[1] = a.y; v[2] = b.x; v[3] = b.y;
        v[4] = c.x; v[5] = c.y; v[6] = d.x; v[7] = d.y;
        v[8] = e.x; v[9] = e.y;
    }
    float s[F];
    #pragma unroll
    for (int f = 0; f < F; ++f) {
        float ra = v[f];
        if (f == 4) ra = __logf(fmaxf(ra * 10.0f, 1e-6f));
        s[f] = (ra - raw_mean[f]) / raw_std[f];
    }
    float acc = 0.0f;
    #pragma unroll
    for (int f = 0; f < F; ++f) {
        float pos = fminf(fmaxf(fmaf(s[f], LUT_INVDX, -LUT_LO * LUT_INVDX), 0.0f), LUT_POSMAX);
        int i = (int)pos;
        float fr = pos - (float)i;
        float2 c = lut1[f * NLUT + i];
        acc += fmaf(fr, c.y - c.x, c.x);
    }
    constexpr float AINV = (float)(NB - 1) / A_SPAN;
    #pragma unroll
    for (int p = 0; p < P; ++p) {
        const float4* lutp = lut2 + p * NB * NB;
        const float binv = (float)(NB - 1) / B_SPAN[p];
        acc += bilerp4(lutp, s[PI[p]], s[PJ[p]], AINV, B_LO[p], binv);
    }
    out[r] = acc;
}

// ============== fallback path B: fully-computed (if ws too small) =========
__global__ __launch_bounds__(256) void risk_full_kernel(
    const float* __restrict__ x,
    const float* __restrict__ raw_mean,
    const float* __restrict__ raw_std,
    const float* __restrict__ fw1,
    const float* __restrict__ fb1,
    const float* __restrict__ fw2,
    const float* __restrict__ fb2,
    const float* __restrict__ pw1,
    const float* __restrict__ pb1,
    const float* __restrict__ pw2,
    const float* __restrict__ pb2,
    float* __restrict__ out,
    int nrows)
{
    const int r = blockIdx.x * blockDim.x + threadIdx.x;
    if (r >= nrows) return;

    float s[F];
    #pragma unroll
    for (int f = 0; f < F; ++f) {
        float ra = x[(size_t)r * F + f];
        if (f == 4) ra = __logf(fmaxf(ra * 10.0f, 1e-6f));
        s[f] = (ra - raw_mean[f]) / raw_std[f];
    }
    float acc = 0.0f;
    #pragma unroll
    for (int f = 0; f < F; ++f) {
        const float* w1 = fw1 + f * H;
        const float* b1 = fb1 + f * H;
        const float* w2 = fw2 + f * H;
        float a0 = 0.0f;
        #pragma unroll 8
        for (int h = 0; h < H; ++h)
            a0 = fmaf(gelu_exact(fmaf(s[f], w1[h], b1[h])), w2[h], a0);
        acc += a0 + fb2[f];
    }
    #pragma unroll
    for (int p = 0; p < P; ++p) {
        const float* wa = pw1 + (p * 2 + 0) * H;
        const float* wb = pw1 + (p * 2 + 1) * H;
        const float* bb = pb1 + p * H;
        const float* w2 = pw2 + p * H;
        const float xa = s[PI[p]], xb = s[PJ[p]];
        float a0 = 0.0f;
        #pragma unroll 8
        for (int h = 0; h < H; ++h)
            a0 = fmaf(gelu_exact(fmaf(xa, wa[h], fmaf(xb, wb[h], bb[h]))), w2[h], a0);
        acc += a0 + pb2[p];
    }
    out[r] = acc;
}

} // namespace

extern "C" void kernel_launch(void* const* d_in, const int* in_sizes, int n_in,
                              void* d_out, int out_size, void* d_ws, size_t ws_size,
                              hipStream_t stream)
{
    const float* x        = (const float*)d_in[0];
    const float* raw_mean = (const float*)d_in[1];
    const float* raw_std  = (const float*)d_in[2];
    const float* fw1      = (const float*)d_in[3];
    const float* fb1      = (const float*)d_in[4];
    const float* fw2      = (const float*)d_in[5];
    const float* fb2      = (const float*)d_in[6];
    const float* pw1      = (const float*)d_in[7];
    const float* pb1      = (const float*)d_in[8];
    const float* pw2      = (const float*)d_in[9];
    const float* pb2      = (const float*)d_in[10];
    float* out = (float*)d_out;

    int nrows = in_sizes[0] / F;                 // 524288
    const int block = 256;
    const int grid = (nrows + block - 1) / block;   // 2048 blocks = 8/CU

    const size_t lut_bytes = (size_t)WS_FLOATS * sizeof(float);
    if (ws_size >= lut_bytes) {
        float* ws = (float*)d_ws;
        void* args[] = {
            (void*)&x, (void*)&raw_mean, (void*)&raw_std,
            (void*)&fw1, (void*)&fb1, (void*)&fw2, (void*)&fb2,
            (void*)&pw1, (void*)&pb1, (void*)&pw2, (void*)&pb2,
            (void*)&ws, (void*)&out, (void*)&nrows
        };
        hipError_t err = hipLaunchCooperativeKernel(
            (const void*)fused_risk_kernel, dim3(grid), dim3(block),
            args, 0, stream);
        if (err != hipSuccess) {
            // fallback: proven two-kernel LUT path (~104 us)
            build_luts<<<(N_ENTRIES + 255) / 256, 256, 0, stream>>>(
                fw1, fb1, fw2, fb2, pw1, pb1, pw2, pb2, ws);
            risk_lut2_kernel<<<grid, block, 0, stream>>>(
                x, raw_mean, raw_std, ws, out, nrows);
        }
    } else {
        risk_full_kernel<<<grid, block, 0, stream>>>(
            x, raw_mean, raw_std, fw1, fb1, fw2, fb2,
            pw1, pb1, pw2, pb2, out, nrows);
    }
}

// Round 15
// 107.275 us; speedup vs baseline: 2.3433x; 2.3433x over previous
//
#include <hip/hip_runtime.h>
#include <math.h>

namespace {

constexpr int F = 10;
constexpr int H = 64;
constexpr int P = 6;

// ---- 1D LUT: only features {4,5,6,8} remain (others folded into 2D) ----
constexpr int F1D = 4;
constexpr int F1D_LIST[F1D] = {4, 5, 6, 8};
constexpr int   NLUT       = 1024;
constexpr float LUT_LO     = -14.5f;     // covers f4 clip point -13.8155
constexpr float LUT_HI     = 6.5f;
constexpr float LUT_DX     = (LUT_HI - LUT_LO) / NLUT;
constexpr float LUT_INVDX  = NLUT / (LUT_HI - LUT_LO);
constexpr float LUT_POSMAX = (float)(NLUT - 2) + 0.999f;

// ---- 2D LUT: NB x NB, quad-packed float4 slots; folded 1D features ----
// slot(p,ia,jb) = (g(ia,jb), g(ia,jb+1), g(ia+1,jb), g(ia+1,jb+1))
// where g = pair_p(sa,sb) + folded_feat contribution
constexpr int NB  = 128;
constexpr int N2D = P * NB * NB;
constexpr float A_LO  = -6.5f;
constexpr float A_SPAN = 13.0f;
constexpr int PI[P] = {0, 0, 0, 0, 1, 2};
constexpr int PJ[P] = {4, 7, 9, 3, 4, 3};
constexpr float B_LO[P]   = {-14.5f, -6.5f, -6.5f, -6.5f, -14.5f, -6.5f};
constexpr float B_SPAN[P] = { 19.0f,  13.0f, 13.0f, 13.0f,  19.0f, 13.0f};
constexpr float POSMAX2   = (float)(NB - 1) - 0.001f;
// folded additive feature per pair table, and which axis it rides on
constexpr int EXF[P] = {0, 7, 9, 3, 1, 2};   // feature id
constexpr int EXA[P] = {0, 1, 1, 1, 0, 0};   // 0 = a-axis (sa), 1 = b-axis (sb)

constexpr int WS_LUT1_OFF = 4 * N2D;
constexpr int WS_FLOATS   = 4 * N2D + 2 * F1D * NLUT;
constexpr int N_ENTRIES   = N2D + F1D * NLUT;   // 102400 build items

// Exact-grade GELU: x * Phi(x), Phi via A&S 7.1.26 erfc (|err| <= 1.5e-7).
__device__ __forceinline__ float gelu_exact(float x) {
    const float kInvSqrt2 = 0.70710678118654752440f;
    float u = x * kInvSqrt2;
    float a = fabsf(u);
    float t = __builtin_amdgcn_rcpf(fmaf(0.3275911f, a, 1.0f));
    float poly = t * fmaf(t, fmaf(t, fmaf(t, fmaf(t, 0.5307027145f,
                                                  -0.7265760135f),
                                           0.7107068705f),
                                   -0.142248368f),
                          0.127414796f);
    float e = __expf(-a * a);
    float half_erfc = poly * e;           // 0.5*erfc(|u|)
    float m = x * half_erfc;
    return (x >= 0.0f) ? (x - m) : m;
}

// additive-path feature MLP: fb2[f] + sum_h fw2[f,h]*gelu(fw1[f,h]*s+fb1[f,h])
__device__ __forceinline__ float feat_mlp(
    int f, float s,
    const float* __restrict__ fw1, const float* __restrict__ fb1,
    const float* __restrict__ fw2, const float* __restrict__ fb2)
{
    const float* w1 = fw1 + f * H;
    const float* b1 = fb1 + f * H;
    const float* w2 = fw2 + f * H;
    float acc = fb2[f];
    #pragma unroll 8
    for (int h = 0; h < H; ++h)
        acc = fmaf(gelu_exact(fmaf(s, w1[h], b1[h])), w2[h], acc);
    return acc;
}

__device__ __forceinline__ void build_entry(
    int idx,
    const float* __restrict__ fw1, const float* __restrict__ fb1,
    const float* __restrict__ fw2, const float* __restrict__ fb2,
    const float* __restrict__ pw1, const float* __restrict__ pb1,
    const float* __restrict__ pw2, const float* __restrict__ pb2,
    float* __restrict__ ws)
{
    if (idx < N2D) {
        const int p   = idx / (NB * NB);
        const int rem = idx - p * (NB * NB);
        const int ia  = rem >> 7;
        const int jb  = rem & (NB - 1);
        const bool f4 = (p == 0) | (p == 4);
        const float blo   = f4 ? -14.5f : -6.5f;
        const float bstep = (f4 ? 19.0f : 13.0f) / (float)(NB - 1);
        const float astep = A_SPAN / (float)(NB - 1);
        const float sa = fmaf((float)ia, astep, A_LO);
        const float sb = fmaf((float)jb, bstep, blo);
        const float* wa = pw1 + (p * 2 + 0) * H;
        const float* wb = pw1 + (p * 2 + 1) * H;
        const float* bb = pb1 + p * H;
        const float* w2 = pw2 + p * H;
        float acc = pb2[p];
        #pragma unroll 8
        for (int h = 0; h < H; ++h) {
            acc = fmaf(gelu_exact(fmaf(sa, wa[h], fmaf(sb, wb[h], bb[h]))),
                       w2[h], acc);
        }
        // fold one additive feature MLP into this table (axis per EXA)
        acc += feat_mlp(EXF[p], EXA[p] ? sb : sa, fw1, fb1, fw2, fb2);

        // scatter into the <=4 quads referencing grid point (ia, jb)
        const int pbase = p * NB * NB;
        float* q = ws + 4 * (pbase + ia * NB + jb);
        q[0] = acc;
        if (jb > 0)           q[-4 + 1] = acc;
        if (ia > 0)           q[-4 * NB + 2] = acc;
        if (ia > 0 && jb > 0) q[-4 * (NB + 1) + 3] = acc;
    } else if (idx < N_ENTRIES) {
        const int k = idx - N2D;
        const int t = k >> 10;               // 0..3
        const int i = k & 1023;
        const int f = F1D_LIST[t];
        const float s = LUT_LO + (float)i * LUT_DX;
        const float acc = feat_mlp(f, s, fw1, fb1, fw2, fb2);
        ws[WS_LUT1_OFF + 2 * k] = acc;               // slot i, .x
        if (i > 0) ws[WS_LUT1_OFF + 2 * k - 1] = acc; // slot i-1, .y
    }
}

__device__ __forceinline__ float bilerp4(const float4* __restrict__ lutp,
                                         float sa, float sb,
                                         float ainv, float blo, float binv) {
    float pa = fminf(fmaxf((sa - A_LO) * ainv, 0.0f), POSMAX2);
    float pb = fminf(fmaxf((sb - blo) * binv, 0.0f), POSMAX2);
    int ia = (int)pa;
    int jb = (int)pb;
    float fa = pa - (float)ia;
    float fb = pb - (float)jb;
    float4 q = lutp[ia * NB + jb];
    float v0 = fmaf(fb, q.y - q.x, q.x);
    float v1 = fmaf(fb, q.w - q.z, q.z);
    return fmaf(fa, v1 - v0, v0);
}

// ---------------- kernel 1: build LUTs ------------------------------------
__global__ __launch_bounds__(256) void build_luts(
    const float* __restrict__ fw1, const float* __restrict__ fb1,
    const float* __restrict__ fw2, const float* __restrict__ fb2,
    const float* __restrict__ pw1, const float* __restrict__ pb1,
    const float* __restrict__ pw2, const float* __restrict__ pb2,
    float* __restrict__ ws)
{
    const int idx = blockIdx.x * blockDim.x + threadIdx.x;
    build_entry(idx, fw1, fb1, fw2, fb2, pw1, pb1, pw2, pb2, ws);
}

// ---------------- kernel 2: eval — 6 bilerps + 4 lerps per row -----------
__global__ __launch_bounds__(256) void risk_lut2_kernel(
    const float* __restrict__ x,
    const float* __restrict__ raw_mean,
    const float* __restrict__ raw_std,
    const float* __restrict__ ws,
    float* __restrict__ out,
    int nrows)
{
    const float4* lut2 = reinterpret_cast<const float4*>(ws);
    const float2* lut1 = reinterpret_cast<const float2*>(ws + WS_LUT1_OFF);
    const int r = blockIdx.x * blockDim.x + threadIdx.x;
    if (r >= nrows) return;

    float v[F];
    {
        const float2* xp = reinterpret_cast<const float2*>(x + (size_t)r * F);
        float2 a = xp[0], b = xp[1], c = xp[2], d = xp[3], e = xp[4];
        v[0] = a.x; v[1] = a.y; v[2] = b.x; v[3] = b.y;
        v[4] = c.x; v[5] = c.y; v[6] = d.x; v[7] = d.y;
        v[8] = e.x; v[9] = e.y;
    }
    float s[F];
    #pragma unroll
    for (int f = 0; f < F; ++f) {
        float ra = v[f];
        if (f == 4) ra = __logf(fmaxf(ra * 10.0f, 1e-6f));
        s[f] = (ra - raw_mean[f]) / raw_std[f];
    }

    float acc = 0.0f;

    // 1D path: features {4,5,6,8}; 32 KB table -> L1-resident
    #pragma unroll
    for (int t = 0; t < F1D; ++t) {
        float pos = fminf(fmaxf(fmaf(s[F1D_LIST[t]], LUT_INVDX,
                                     -LUT_LO * LUT_INVDX), 0.0f), LUT_POSMAX);
        int i = (int)pos;
        float fr = pos - (float)i;
        float2 c = lut1[t * NLUT + i];
        acc += fmaf(fr, c.y - c.x, c.x);
    }

    // 2D path: one float4 bilerp per pair (folded features + pb2 baked in)
    constexpr float AINV = (float)(NB - 1) / A_SPAN;
    #pragma unroll
    for (int p = 0; p < P; ++p) {
        const float4* lutp = lut2 + p * NB * NB;
        const float binv = (float)(NB - 1) / B_SPAN[p];
        acc += bilerp4(lutp, s[PI[p]], s[PJ[p]], AINV, B_LO[p], binv);
    }

    out[r] = acc;
}

// ---------------- fallback: fully-computed kernel (if ws too small) -------
__global__ __launch_bounds__(256) void risk_full_kernel(
    const float* __restrict__ x,
    const float* __restrict__ raw_mean,
    const float* __restrict__ raw_std,
    const float* __restrict__ fw1,
    const float* __restrict__ fb1,
    const float* __restrict__ fw2,
    const float* __restrict__ fb2,
    const float* __restrict__ pw1,
    const float* __restrict__ pb1,
    const float* __restrict__ pw2,
    const float* __restrict__ pb2,
    float* __restrict__ out,
    int nrows)
{
    const int r = blockIdx.x * blockDim.x + threadIdx.x;
    if (r >= nrows) return;

    float s[F];
    #pragma unroll
    for (int f = 0; f < F; ++f) {
        float ra = x[(size_t)r * F + f];
        if (f == 4) ra = __logf(fmaxf(ra * 10.0f, 1e-6f));
        s[f] = (ra - raw_mean[f]) / raw_std[f];
    }
    float acc = 0.0f;
    #pragma unroll
    for (int f = 0; f < F; ++f) {
        acc += feat_mlp(f, s[f], fw1, fb1, fw2, fb2);
    }
    #pragma unroll
    for (int p = 0; p < P; ++p) {
        const float* wa = pw1 + (p * 2 + 0) * H;
        const float* wb = pw1 + (p * 2 + 1) * H;
        const float* bb = pb1 + p * H;
        const float* w2 = pw2 + p * H;
        const float xa = s[PI[p]], xb = s[PJ[p]];
        float a0 = 0.0f;
        #pragma unroll 8
        for (int h = 0; h < H; ++h)
            a0 = fmaf(gelu_exact(fmaf(xa, wa[h], fmaf(xb, wb[h], bb[h]))), w2[h], a0);
        acc += a0 + pb2[p];
    }
    out[r] = acc;
}

} // namespace

extern "C" void kernel_launch(void* const* d_in, const int* in_sizes, int n_in,
                              void* d_out, int out_size, void* d_ws, size_t ws_size,
                              hipStream_t stream)
{
    const float* x        = (const float*)d_in[0];
    const float* raw_mean = (const float*)d_in[1];
    const float* raw_std  = (const float*)d_in[2];
    const float* fw1      = (const float*)d_in[3];
    const float* fb1      = (const float*)d_in[4];
    const float* fw2      = (const float*)d_in[5];
    const float* fb2      = (const float*)d_in[6];
    const float* pw1      = (const float*)d_in[7];
    const float* pb1      = (const float*)d_in[8];
    const float* pw2      = (const float*)d_in[9];
    const float* pb2      = (const float*)d_in[10];
    float* out = (float*)d_out;

    const int nrows = in_sizes[0] / F;           // 524288
    const int block = 256;
    const int grid = (nrows + block - 1) / block;   // 2048 blocks

    const size_t lut_bytes = (size_t)WS_FLOATS * sizeof(float);
    if (ws_size >= lut_bytes) {
        float* ws = (float*)d_ws;
        build_luts<<<(N_ENTRIES + 255) / 256, 256, 0, stream>>>(
            fw1, fb1, fw2, fb2, pw1, pb1, pw2, pb2, ws);
        risk_lut2_kernel<<<grid, block, 0, stream>>>(
            x, raw_mean, raw_std, ws, out, nrows);
    } else {
        risk_full_kernel<<<grid, block, 0, stream>>>(
            x, raw_mean, raw_std, fw1, fb1, fw2, fb2,
            pw1, pb1, pw2, pb2, out, nrows);
    }
}

// Round 16
// 102.966 us; speedup vs baseline: 2.4413x; 1.0419x over previous
//
#include <hip/hip_runtime.h>
#include <math.h>

namespace {

constexpr int F = 10;
constexpr int H = 64;
constexpr int P = 6;

// ---- 1D LUT: all 10 features, UNPACKED floats (LDS-staged in eval) ----
constexpr int   NLUT       = 1024;
constexpr float LUT_LO     = -14.5f;     // covers f4 clip point -13.8155
constexpr float LUT_HI     = 6.5f;
constexpr float LUT_DX     = (LUT_HI - LUT_LO) / NLUT;
constexpr float LUT_INVDX  = NLUT / (LUT_HI - LUT_LO);
constexpr float LUT_POSMAX = (float)(NLUT - 2) + 0.999f;

// ---- 2D LUT: NB x NB grid, quad-packed float4 slots (pure pair MLP) ----
// slot(p,ia,jb) = (f(ia,jb), f(ia,jb+1), f(ia+1,jb), f(ia+1,jb+1))
constexpr int NB  = 128;
constexpr int N2D = P * NB * NB;
constexpr float A_LO  = -6.5f;
constexpr float A_SPAN = 13.0f;
constexpr int PI[P] = {0, 0, 0, 0, 1, 2};
constexpr int PJ[P] = {4, 7, 9, 3, 4, 3};
constexpr float B_LO[P]   = {-14.5f, -6.5f, -6.5f, -6.5f, -14.5f, -6.5f};
constexpr float B_SPAN[P] = { 19.0f,  13.0f, 13.0f, 13.0f,  19.0f, 13.0f};
constexpr float POSMAX2   = (float)(NB - 1) - 0.001f;

// ws layout (floats):
//   [0, 4*N2D)               : lut2 quads
//   [4*N2D, 4*N2D + F*NLUT)  : lut1 unpacked (10240 floats = 40 KB)
constexpr int WS_LUT1_OFF = 4 * N2D;
constexpr int WS_FLOATS   = 4 * N2D + F * NLUT;
constexpr int N_ENTRIES   = N2D + F * NLUT;   // 108544 build items

// Exact-grade GELU: x * Phi(x), Phi via A&S 7.1.26 erfc (|err| <= 1.5e-7).
__device__ __forceinline__ float gelu_exact(float x) {
    const float kInvSqrt2 = 0.70710678118654752440f;
    float u = x * kInvSqrt2;
    float a = fabsf(u);
    float t = __builtin_amdgcn_rcpf(fmaf(0.3275911f, a, 1.0f));
    float poly = t * fmaf(t, fmaf(t, fmaf(t, fmaf(t, 0.5307027145f,
                                                  -0.7265760135f),
                                           0.7107068705f),
                                   -0.142248368f),
                          0.127414796f);
    float e = __expf(-a * a);
    float half_erfc = poly * e;           // 0.5*erfc(|u|)
    float m = x * half_erfc;
    return (x >= 0.0f) ? (x - m) : m;
}

// additive-path feature MLP
__device__ __forceinline__ float feat_mlp(
    int f, float s,
    const float* __restrict__ fw1, const float* __restrict__ fb1,
    const float* __restrict__ fw2, const float* __restrict__ fb2)
{
    const float* w1 = fw1 + f * H;
    const float* b1 = fb1 + f * H;
    const float* w2 = fw2 + f * H;
    float acc = fb2[f];
    #pragma unroll 8
    for (int h = 0; h < H; ++h)
        acc = fmaf(gelu_exact(fmaf(s, w1[h], b1[h])), w2[h], acc);
    return acc;
}

__device__ __forceinline__ void build_entry(
    int idx,
    const float* __restrict__ fw1, const float* __restrict__ fb1,
    const float* __restrict__ fw2, const float* __restrict__ fb2,
    const float* __restrict__ pw1, const float* __restrict__ pb1,
    const float* __restrict__ pw2, const float* __restrict__ pb2,
    float* __restrict__ ws)
{
    if (idx < N2D) {
        const int p   = idx / (NB * NB);
        const int rem = idx - p * (NB * NB);
        const int ia  = rem >> 7;
        const int jb  = rem & (NB - 1);
        const bool f4 = (p == 0) | (p == 4);
        const float blo   = f4 ? -14.5f : -6.5f;
        const float bstep = (f4 ? 19.0f : 13.0f) / (float)(NB - 1);
        const float astep = A_SPAN / (float)(NB - 1);
        const float sa = fmaf((float)ia, astep, A_LO);
        const float sb = fmaf((float)jb, bstep, blo);
        const float* wa = pw1 + (p * 2 + 0) * H;
        const float* wb = pw1 + (p * 2 + 1) * H;
        const float* bb = pb1 + p * H;
        const float* w2 = pw2 + p * H;
        float acc = pb2[p];
        #pragma unroll 8
        for (int h = 0; h < H; ++h) {
            acc = fmaf(gelu_exact(fmaf(sa, wa[h], fmaf(sb, wb[h], bb[h]))),
                       w2[h], acc);
        }
        // scatter into the <=4 quads referencing grid point (ia, jb)
        const int pbase = p * NB * NB;
        float* q = ws + 4 * (pbase + ia * NB + jb);
        q[0] = acc;
        if (jb > 0)           q[-4 + 1] = acc;
        if (ia > 0)           q[-4 * NB + 2] = acc;
        if (ia > 0 && jb > 0) q[-4 * (NB + 1) + 3] = acc;
    } else if (idx < N_ENTRIES) {
        const int k = idx - N2D;
        const int f = k >> 10;
        const int i = k & 1023;
        const float s = LUT_LO + (float)i * LUT_DX;
        ws[WS_LUT1_OFF + k] = feat_mlp(f, s, fw1, fb1, fw2, fb2);
    }
}

__device__ __forceinline__ float bilerp4(const float4* __restrict__ lutp,
                                         float sa, float sb,
                                         float ainv, float blo, float binv) {
    float pa = fminf(fmaxf((sa - A_LO) * ainv, 0.0f), POSMAX2);
    float pb = fminf(fmaxf((sb - blo) * binv, 0.0f), POSMAX2);
    int ia = (int)pa;
    int jb = (int)pb;
    float fa = pa - (float)ia;
    float fb = pb - (float)jb;
    float4 q = lutp[ia * NB + jb];
    float v0 = fmaf(fb, q.y - q.x, q.x);
    float v1 = fmaf(fb, q.w - q.z, q.z);
    return fmaf(fa, v1 - v0, v0);
}

// ---------------- kernel 1: build LUTs ------------------------------------
__global__ __launch_bounds__(256) void build_luts(
    const float* __restrict__ fw1, const float* __restrict__ fb1,
    const float* __restrict__ fw2, const float* __restrict__ fb2,
    const float* __restrict__ pw1, const float* __restrict__ pb1,
    const float* __restrict__ pw2, const float* __restrict__ pb2,
    float* __restrict__ ws)
{
    const int idx = blockIdx.x * blockDim.x + threadIdx.x;
    build_entry(idx, fw1, fb1, fw2, fb2, pw1, pb1, pw2, pb2, ws);
}

// ---------------- kernel 2: eval — LDS 1D lerps + 6 VMEM bilerps ---------
__global__ __launch_bounds__(256) void risk_lut2_kernel(
    const float* __restrict__ x,
    const float* __restrict__ raw_mean,
    const float* __restrict__ raw_std,
    const float* __restrict__ ws,
    float* __restrict__ out,
    int nrows)
{
    __shared__ float slut[F * NLUT];   // 40 KiB -> 4 blocks/CU
    const float4* lut2 = reinterpret_cast<const float4*>(ws);

    // stage 1D LUT: 10240 floats = 2560 float4 = 10 per thread, coalesced
    {
        const float4* g = reinterpret_cast<const float4*>(ws + WS_LUT1_OFF);
        float4* l = reinterpret_cast<float4*>(slut);
        #pragma unroll
        for (int i = 0; i < (F * NLUT) / 4 / 256; ++i)
            l[threadIdx.x + i * 256] = g[threadIdx.x + i * 256];
    }
    __syncthreads();

    const int r = blockIdx.x * blockDim.x + threadIdx.x;
    if (r >= nrows) return;

    float v[F];
    {
        const float2* xp = reinterpret_cast<const float2*>(x + (size_t)r * F);
        float2 a = xp[0], b = xp[1], c = xp[2], d = xp[3], e = xp[4];
        v[0] = a.x; v[1] = a.y; v[2] = b.x; v[3] = b.y;
        v[4] = c.x; v[5] = c.y; v[6] = d.x; v[7] = d.y;
        v[8] = e.x; v[9] = e.y;
    }
    float s[F];
    #pragma unroll
    for (int f = 0; f < F; ++f) {
        float ra = v[f];
        if (f == 4) ra = __logf(fmaxf(ra * 10.0f, 1e-6f));
        s[f] = (ra - raw_mean[f]) / raw_std[f];
    }

    float acc = 0.0f;

    // 1D path: LDS lerp per feature (fb2 baked into table)
    #pragma unroll
    for (int f = 0; f < F; ++f) {
        float pos = fminf(fmaxf(fmaf(s[f], LUT_INVDX, -LUT_LO * LUT_INVDX),
                                0.0f), LUT_POSMAX);
        int i = (int)pos;
        float fr = pos - (float)i;
        float a = slut[f * NLUT + i];
        float b = slut[f * NLUT + i + 1];
        acc += fmaf(fr, b - a, a);
    }

    // 2D path: one float4 bilerp per pair (pb2 baked in)
    constexpr float AINV = (float)(NB - 1) / A_SPAN;
    #pragma unroll
    for (int p = 0; p < P; ++p) {
        const float4* lutp = lut2 + p * NB * NB;
        const float binv = (float)(NB - 1) / B_SPAN[p];
        acc += bilerp4(lutp, s[PI[p]], s[PJ[p]], AINV, B_LO[p], binv);
    }

    out[r] = acc;
}

// ---------------- fallback: fully-computed kernel (if ws too small) -------
__global__ __launch_bounds__(256) void risk_full_kernel(
    const float* __restrict__ x,
    const float* __restrict__ raw_mean,
    const float* __restrict__ raw_std,
    const float* __restrict__ fw1,
    const float* __restrict__ fb1,
    const float* __restrict__ fw2,
    const float* __restrict__ fb2,
    const float* __restrict__ pw1,
    const float* __restrict__ pb1,
    const float* __restrict__ pw2,
    const float* __restrict__ pb2,
    float* __restrict__ out,
    int nrows)
{
    const int r = blockIdx.x * blockDim.x + threadIdx.x;
    if (r >= nrows) return;

    float s[F];
    #pragma unroll
    for (int f = 0; f < F; ++f) {
        float ra = x[(size_t)r * F + f];
        if (f == 4) ra = __logf(fmaxf(ra * 10.0f, 1e-6f));
        s[f] = (ra - raw_mean[f]) / raw_std[f];
    }
    float acc = 0.0f;
    #pragma unroll
    for (int f = 0; f < F; ++f) {
        acc += feat_mlp(f, s[f], fw1, fb1, fw2, fb2);
    }
    #pragma unroll
    for (int p = 0; p < P; ++p) {
        const float* wa = pw1 + (p * 2 + 0) * H;
        const float* wb = pw1 + (p * 2 + 1) * H;
        const float* bb = pb1 + p * H;
        const float* w2 = pw2 + p * H;
        const float xa = s[PI[p]], xb = s[PJ[p]];
        float a0 = 0.0f;
        #pragma unroll 8
        for (int h = 0; h < H; ++h)
            a0 = fmaf(gelu_exact(fmaf(xa, wa[h], fmaf(xb, wb[h], bb[h]))), w2[h], a0);
        acc += a0 + pb2[p];
    }
    out[r] = acc;
}

} // namespace

extern "C" void kernel_launch(void* const* d_in, const int* in_sizes, int n_in,
                              void* d_out, int out_size, void* d_ws, size_t ws_size,
                              hipStream_t stream)
{
    const float* x        = (const float*)d_in[0];
    const float* raw_mean = (const float*)d_in[1];
    const float* raw_std  = (const float*)d_in[2];
    const float* fw1      = (const float*)d_in[3];
    const float* fb1      = (const float*)d_in[4];
    const float* fw2      = (const float*)d_in[5];
    const float* fb2      = (const float*)d_in[6];
    const float* pw1      = (const float*)d_in[7];
    const float* pb1      = (const float*)d_in[8];
    const float* pw2      = (const float*)d_in[9];
    const float* pb2      = (const float*)d_in[10];
    float* out = (float*)d_out;

    const int nrows = in_sizes[0] / F;           // 524288
    const int block = 256;
    const int grid = (nrows + block - 1) / block;   // 2048 blocks

    const size_t lut_bytes = (size_t)WS_FLOATS * sizeof(float);
    if (ws_size >= lut_bytes) {
        float* ws = (float*)d_ws;
        build_luts<<<(N_ENTRIES + 255) / 256, 256, 0, stream>>>(
            fw1, fb1, fw2, fb2, pw1, pb1, pw2, pb2, ws);
        risk_lut2_kernel<<<grid, block, 0, stream>>>(
            x, raw_mean, raw_std, ws, out, nrows);
    } else {
        risk_full_kernel<<<grid, block, 0, stream>>>(
            x, raw_mean, raw_std, fw1, fb1, fw2, fb2,
            pw1, pb1, pw2, pb2, out, nrows);
    }
}